// Round 3
// baseline (715.218 us; speedup 1.0000x reference)
//
#include <hip/hip_runtime.h>

#define NNODES 20000
#define NEDGES 200000

// ---------------------------------------------------------------------------
// Zero-fill (float4 granularity). n4 = number of float4 elements.
// ---------------------------------------------------------------------------
__global__ __launch_bounds__(256)
void zero_kernel(float4* __restrict__ p, long n4)
{
    long i = (long)blockIdx.x * 256 + threadIdx.x;
    if (i < n4) p[i] = make_float4(0.f, 0.f, 0.f, 0.f);
}

// ---------------------------------------------------------------------------
// Generic tiled linear: out[r, j] = act( x[r,:] @ W[:,j] + bias[j] (+ gathers) )
//  - 4x4 per-thread micro-tile, BR = 16*BLOCK/DOUT rows per block
//  - x staged TRANSPOSED in LDS (stride BR+1 -> conflict-free), W staged in LDS
//  - DIV:      x element-wise = x/xden (0 where xden<=0)  [softmax denominator]
//  - EDGEADD:  out += tabA[idxA[r]] + tabB[idxB[r]]       [edge gather-add]
// ---------------------------------------------------------------------------
template<int DIN, int DOUT, int BLOCK, bool RELU, bool DIV, bool EDGEADD>
__global__ __launch_bounds__(BLOCK)
void linear_kernel(const float* __restrict__ x,
                   const float* __restrict__ xden,
                   const float* __restrict__ W,
                   const float* __restrict__ bias,
                   const float* __restrict__ tabA,
                   const float* __restrict__ tabB,
                   const int* __restrict__ idxA,
                   const int* __restrict__ idxB,
                   float* __restrict__ out,
                   int nrows, int out_stride)
{
    constexpr int BR  = 16 * BLOCK / DOUT;  // rows per block
    constexpr int BRP = BR + 1;             // pad: LDS bank-conflict-free
    constexpr int KV  = DIN / 4;            // float4 chunks per input row
    constexpr int JT  = DOUT / 4;           // col groups

    __shared__ float xs[DIN * BRP];         // transposed x tile
    __shared__ float Ws[DIN * DOUT];

    const int tid  = threadIdx.x;
    const int row0 = blockIdx.x * BR;

    // stage W (contiguous float4 copy)
    for (int i = tid; i < DIN * DOUT / 4; i += BLOCK)
        ((float4*)Ws)[i] = ((const float4*)W)[i];

    // stage x transposed: xs[k*BRP + r] = x[row0+r][k]
    const int kv = tid % KV;
    for (int rr = tid / KV; rr < BR; rr += BLOCK / KV) {
        const int row = row0 + rr;
        float4 v = make_float4(0.f, 0.f, 0.f, 0.f);
        if (row < nrows) {
            v = ((const float4*)x)[(long)row * KV + kv];
            if (DIV) {
                float4 dv = ((const float4*)xden)[(long)row * KV + kv];
                v.x = dv.x > 0.f ? v.x / dv.x : 0.f;
                v.y = dv.y > 0.f ? v.y / dv.y : 0.f;
                v.z = dv.z > 0.f ? v.z / dv.z : 0.f;
                v.w = dv.w > 0.f ? v.w / dv.w : 0.f;
            }
        }
        xs[(kv * 4 + 0) * BRP + rr] = v.x;
        xs[(kv * 4 + 1) * BRP + rr] = v.y;
        xs[(kv * 4 + 2) * BRP + rr] = v.z;
        xs[(kv * 4 + 3) * BRP + rr] = v.w;
    }
    __syncthreads();

    const int jt = tid % JT;
    const int rt = tid / JT;

    float4 b4 = ((const float4*)bias)[jt];
    float acc[4][4];
    #pragma unroll
    for (int r = 0; r < 4; ++r) {
        acc[r][0] = b4.x; acc[r][1] = b4.y; acc[r][2] = b4.z; acc[r][3] = b4.w;
    }

    #pragma unroll 8
    for (int k = 0; k < DIN; ++k) {
        float4 w = ((const float4*)(Ws + k * DOUT))[jt];
        float xr[4];
        #pragma unroll
        for (int r = 0; r < 4; ++r) xr[r] = xs[k * BRP + rt * 4 + r];
        #pragma unroll
        for (int r = 0; r < 4; ++r) {
            acc[r][0] = fmaf(xr[r], w.x, acc[r][0]);
            acc[r][1] = fmaf(xr[r], w.y, acc[r][1]);
            acc[r][2] = fmaf(xr[r], w.z, acc[r][2]);
            acc[r][3] = fmaf(xr[r], w.w, acc[r][3]);
        }
    }

    #pragma unroll
    for (int r = 0; r < 4; ++r) {
        const int row = row0 + rt * 4 + r;
        if (row >= nrows) continue;
        float4 o = make_float4(acc[r][0], acc[r][1], acc[r][2], acc[r][3]);
        if (EDGEADD) {
            const int a = idxA[row];
            const int b = idxB[row];
            float4 ga = ((const float4*)(tabA + (long)a * DOUT))[jt];
            float4 gb = ((const float4*)(tabB + (long)b * DOUT))[jt];
            o.x += ga.x + gb.x; o.y += ga.y + gb.y;
            o.z += ga.z + gb.z; o.w += ga.w + gb.w;
        }
        if (RELU) {
            o.x = fmaxf(o.x, 0.f); o.y = fmaxf(o.y, 0.f);
            o.z = fmaxf(o.z, 0.f); o.w = fmaxf(o.w, 0.f);
        }
        *((float4*)(out + (long)row * out_stride) + jt) = o;
    }
}

// ---------------------------------------------------------------------------
// Attention pass (one per direction). Max-subtraction cancels algebraically
// (exp(x-m)/sum exp(x-m) == exp(x)/sum exp(x)); |x| <~ 15 so exp cannot
// overflow fp32. Division deferred to the per-node final linear:
//   agg = (sum hve*e) / (sum e).
//   hve[c] = c<64 ? feat_node[src][c] : feat_edge[e][c-64]
//   p = exp(hve * h_att[src][c]); segsum[dst][c]+=p; aggnum[dst][c]+=hve*p
// ---------------------------------------------------------------------------
__global__ __launch_bounds__(256)
void att_kernel(const float* __restrict__ feat_node,
                const float* __restrict__ feat_edge,
                const float* __restrict__ h_att,
                const int* __restrict__ src,
                const int* __restrict__ dst,
                float* __restrict__ segsum,
                float* __restrict__ aggnum,
                int nedges)
{
    const int t = blockIdx.x * 256 + threadIdx.x;
    const int e = t >> 7;        // 128 channels per edge
    const int c = t & 127;
    if (e >= nedges) return;
    const int s = src[e];
    const int d = dst[e];
    // c<64 -> lanes 0..63 of the 128-group: wave-uniform branch
    const float hve = (c < 64) ? feat_node[(long)s * 64 + c]
                               : feat_edge[(long)e * 64 + (c - 64)];
    const float att = h_att[(long)s * 128 + c];
    const float p = __expf(hve * att);
    unsafeAtomicAdd(&segsum[(long)d * 128 + c], p);
    unsafeAtomicAdd(&aggnum[(long)d * 128 + c], hve * p);
}

// ---------------------------------------------------------------------------
extern "C" void kernel_launch(void* const* d_in, const int* in_sizes, int n_in,
                              void* d_out, int out_size, void* d_ws, size_t ws_size,
                              hipStream_t stream)
{
    const float* f_feat = (const float*)d_in[0];
    const float* b_feat = (const float*)d_in[1];
    const float* u_feat = (const float*)d_in[2];
    const float* v_feat = (const float*)d_in[3];
    const int* fw_src = (const int*)d_in[4];
    const int* fw_dst = (const int*)d_in[5];
    const int* bw_src = (const int*)d_in[6];
    const int* bw_dst = (const int*)d_in[7];
    const float* w_e  = (const float*)d_in[8];   const float* b_e  = (const float*)d_in[9];
    const float* w_u  = (const float*)d_in[10];  const float* b_u  = (const float*)d_in[11];
    const float* w_v  = (const float*)d_in[12];  const float* b_v  = (const float*)d_in[13];
    const float* w_au = (const float*)d_in[14];  const float* b_au = (const float*)d_in[15];
    const float* w_av = (const float*)d_in[16];  const float* b_av = (const float*)d_in[17];
    const float* w_Wu = (const float*)d_in[18];  const float* b_Wu = (const float*)d_in[19];
    const float* w_Wv = (const float*)d_in[20];  const float* b_Wv = (const float*)d_in[21];
    const float* w_Vu = (const float*)d_in[22];  const float* b_Vu = (const float*)d_in[23];
    const float* w_Vv = (const float*)d_in[24];  const float* b_Vv = (const float*)d_in[25];

    const int N = NNODES, E = NEDGES;

    // outputs: (hf, hb, hu, hv) concatenated flat
    float* out = (float*)d_out;
    float* hf = out;                       // [E,64]  (written LAST)
    float* hb = hf + (long)E * 64;         // [E,64]  (written LAST)
    float* hu = hb + (long)E * 64;         // [N,128]
    float* hv = hu + (long)N * 128;        // [N,128]

    // h_att_u / h_att_v staged in the hf region of d_out (2*N*128 = 5.12M
    // floats < E*64 = 12.8M). Consumed by the att passes, then hf is
    // overwritten by the edge linears at the end.
    float* h_att_u = hf;                   // [N,128]
    float* h_att_v = h_att_u + (long)N * 128;

    // workspace layout (floats): 3*N*64 + 4*N*128 = 704*N = 56.3 MB
    const size_t ws_need = (size_t)704 * N * sizeof(float);
    if (ws_size < ws_need) return;         // defensive: avoid OOB scribbling

    float* ws = (float*)d_ws;
    float* src_he_u = ws;                        // [N,64] (== dst_he_u)
    float* src_he_v = src_he_u + (long)N * 64;   // [N,64]
    float* dst_he_v = src_he_v + (long)N * 64;   // [N,64]
    float* segsum_u = dst_he_v + (long)N * 64;   // [N,128] zeroed
    float* aggnum_u = segsum_u + (long)N * 128;  // [N,128] zeroed
    float* segsum_v = aggnum_u + (long)N * 128;  // [N,128] zeroed
    float* aggnum_v = segsum_v + (long)N * 128;  // [N,128] zeroed

    // zero the atomic accumulators (4*N*128 floats contiguous = 2.56M float4)
    {
        const long n4 = (long)4 * N * 128 / 4;
        zero_kernel<<<dim3((n4 + 255) / 256), dim3(256), 0, stream>>>(
            (float4*)segsum_u, n4);
    }

    const int gN64 = (N + 63) / 64;  // DOUT=64, BLOCK=256 -> BR=64
    const int gN32 = (N + 31) / 32;  // BR=32 variants
    const int gE64 = (E + 63) / 64;

    // node projections (into ws)
    hipLaunchKernelGGL((linear_kernel<64,64,256,false,false,false>), dim3(gN64), dim3(256), 0, stream,
                       u_feat, nullptr, w_u,  b_u,  nullptr, nullptr, nullptr, nullptr, src_he_u, N, 64);
    hipLaunchKernelGGL((linear_kernel<64,64,256,false,false,false>), dim3(gN64), dim3(256), 0, stream,
                       v_feat, nullptr, w_v,  b_v,  nullptr, nullptr, nullptr, nullptr, src_he_v, N, 64);
    hipLaunchKernelGGL((linear_kernel<64,64,256,false,false,false>), dim3(gN64), dim3(256), 0, stream,
                       v_feat, nullptr, w_u,  b_u,  nullptr, nullptr, nullptr, nullptr, dst_he_v, N, 64);
    hipLaunchKernelGGL((linear_kernel<64,128,256,false,false,false>), dim3(gN32), dim3(256), 0, stream,
                       u_feat, nullptr, w_au, b_au, nullptr, nullptr, nullptr, nullptr, h_att_u, N, 128);
    hipLaunchKernelGGL((linear_kernel<64,128,256,false,false,false>), dim3(gN32), dim3(256), 0, stream,
                       v_feat, nullptr, w_av, b_av, nullptr, nullptr, nullptr, nullptr, h_att_v, N, 128);

    // hu/hv left halves (direct to d_out, stride 128)
    hipLaunchKernelGGL((linear_kernel<64,64,256,false,false,false>), dim3(gN64), dim3(256), 0, stream,
                       u_feat, nullptr, w_Vu, b_Vu, nullptr, nullptr, nullptr, nullptr, hu, N, 128);
    hipLaunchKernelGGL((linear_kernel<64,64,256,false,false,false>), dim3(gN64), dim3(256), 0, stream,
                       v_feat, nullptr, w_Vv, b_Vv, nullptr, nullptr, nullptr, nullptr, hv, N, 128);

    // attention passes (atomics into segsum/aggnum; h_att read from hf region)
    const int gAtt = (int)(((long)E * 128 + 255) / 256);
    hipLaunchKernelGGL(att_kernel, dim3(gAtt), dim3(256), 0, stream,
                       v_feat, b_feat, h_att_u, bw_src, bw_dst, segsum_u, aggnum_u, E);
    hipLaunchKernelGGL(att_kernel, dim3(gAtt), dim3(256), 0, stream,
                       u_feat, f_feat, h_att_v, fw_src, fw_dst, segsum_v, aggnum_v, E);

    // final: h_n = relu((aggnum/segsum) @ w_W + b_W) -> right halves of hu/hv
    hipLaunchKernelGGL((linear_kernel<128,64,128,true,true,false>), dim3(gN32), dim3(128), 0, stream,
                       aggnum_u, segsum_u, w_Wu, b_Wu, nullptr, nullptr, nullptr, nullptr, hu + 64, N, 128);
    hipLaunchKernelGGL((linear_kernel<128,64,128,true,true,false>), dim3(gN32), dim3(128), 0, stream,
                       aggnum_v, segsum_v, w_Wv, b_Wv, nullptr, nullptr, nullptr, nullptr, hv + 64, N, 128);

    // edge outputs LAST (they overwrite the h_att scratch in hf):
    // hf = relu(b_feat@w_e + b_e + src_he_u[bw_src] + src_he_v[bw_dst])
    hipLaunchKernelGGL((linear_kernel<64,64,256,true,false,true>), dim3(gE64), dim3(256), 0, stream,
                       b_feat, nullptr, w_e, b_e, src_he_u, src_he_v, bw_src, bw_dst, hf, E, 64);
    // hb = relu(f_feat@w_e + b_e + src_he_u[fw_src] + dst_he_v[fw_dst])
    hipLaunchKernelGGL((linear_kernel<64,64,256,true,false,true>), dim3(gE64), dim3(256), 0, stream,
                       f_feat, nullptr, w_e, b_e, src_he_u, dst_he_v, fw_src, fw_dst, hb, E, 64);
}

// Round 4
// 620.323 us; speedup vs baseline: 1.1530x; 1.1530x over previous
//
#include <hip/hip_runtime.h>

#define NNODES 20000
#define NEDGES 200000

// ---------------------------------------------------------------------------
// Zero-fill (float4 granularity). n4 = number of float4 elements.
// ---------------------------------------------------------------------------
__global__ __launch_bounds__(256)
void zero_kernel(float4* __restrict__ p, long n4)
{
    long i = (long)blockIdx.x * 256 + threadIdx.x;
    if (i < n4) p[i] = make_float4(0.f, 0.f, 0.f, 0.f);
}

// ---------------------------------------------------------------------------
// CSR build: histogram -> single-block scan -> scatter
// ---------------------------------------------------------------------------
__global__ __launch_bounds__(256)
void hist_kernel(const int* __restrict__ dst, int* __restrict__ deg, int n)
{
    int e = blockIdx.x * 256 + threadIdx.x;
    if (e < n) atomicAdd(&deg[dst[e]], 1);
}

// exclusive scan of deg[0..n) -> rowptr[0..n], also copies into cursor.
// single block of 1024 threads, each owns a CH-element chunk.
__global__ __launch_bounds__(1024)
void scan_kernel(const int* __restrict__ deg, int* __restrict__ rowptr,
                 int* __restrict__ cursor, int n)
{
    __shared__ int part[1024];
    const int t  = threadIdx.x;
    const int CH = (n + 1023) / 1024;
    const int base = t * CH;

    int s = 0;
    for (int i = 0; i < CH; ++i) {
        int idx = base + i;
        if (idx < n) s += deg[idx];
    }
    part[t] = s;
    __syncthreads();
    // Hillis-Steele inclusive scan
    for (int off = 1; off < 1024; off <<= 1) {
        int v = 0;
        if (t >= off) v = part[t - off];
        __syncthreads();
        if (t >= off) part[t] += v;
        __syncthreads();
    }
    int run = (t == 0) ? 0 : part[t - 1];
    for (int i = 0; i < CH; ++i) {
        int idx = base + i;
        if (idx < n) {
            int dv = deg[idx];
            rowptr[idx] = run;
            cursor[idx] = run;
            run += dv;
        }
    }
    if (t == 1023) rowptr[n] = part[1023];
}

__global__ __launch_bounds__(256)
void scatter_kernel(const int* __restrict__ dst, int* __restrict__ cursor,
                    int* __restrict__ eidx, int n)
{
    int e = blockIdx.x * 256 + threadIdx.x;
    if (e < n) {
        int p = atomicAdd(&cursor[dst[e]], 1);
        eidx[p] = e;
    }
}

// ---------------------------------------------------------------------------
// Segmented attention-aggregation. One 128-thread block per dst node d;
// thread c owns channel c. Max-subtraction cancels algebraically
// (exp(x-m)/sum exp(x-m) == exp(x)/sum exp(x)); |x| small so no fp32
// overflow. Writes agg = (sum hve*p)/(sum p) once per node — no atomics.
//   hve[c] = c<64 ? feat_node[src][c] : feat_edge[e][c-64]
// Empty segment -> 0 (matches segment_sum over empty set).
// ---------------------------------------------------------------------------
__global__ __launch_bounds__(128)
void agg_kernel(const float* __restrict__ feat_node,
                const float* __restrict__ feat_edge,
                const float* __restrict__ h_att,
                const int* __restrict__ src,
                const int* __restrict__ eidx,
                const int* __restrict__ rowptr,
                float* __restrict__ agg)
{
    const int d = blockIdx.x;
    const int c = threadIdx.x;
    const int lo = rowptr[d], hi = rowptr[d + 1];
    const bool low = c < 64;
    float ssum = 0.f, anum = 0.f;
    for (int i = lo; i < hi; ++i) {
        const int e = eidx[i];
        const int s = src[e];
        const float hve = low ? feat_node[(long)s * 64 + c]
                              : feat_edge[(long)e * 64 + (c - 64)];
        const float att = h_att[(long)s * 128 + c];
        const float p = __expf(hve * att);
        ssum += p;
        anum += hve * p;
    }
    agg[(long)d * 128 + c] = (hi > lo) ? anum / ssum : 0.f;
}

// ---------------------------------------------------------------------------
// Generic tiled linear: out[r, j] = act( x[r,:] @ W[:,j] + bias[j] (+ gathers) )
//  - 4x4 per-thread micro-tile, BR = 16*BLOCK/DOUT rows per block
//  - x staged TRANSPOSED in LDS (stride BR+1 -> conflict-free), W staged in LDS
//  - EDGEADD:  out += tabA[idxA[r]] + tabB[idxB[r]]       [edge gather-add]
// ---------------------------------------------------------------------------
template<int DIN, int DOUT, int BLOCK, bool RELU, bool EDGEADD>
__global__ __launch_bounds__(BLOCK)
void linear_kernel(const float* __restrict__ x,
                   const float* __restrict__ W,
                   const float* __restrict__ bias,
                   const float* __restrict__ tabA,
                   const float* __restrict__ tabB,
                   const int* __restrict__ idxA,
                   const int* __restrict__ idxB,
                   float* __restrict__ out,
                   int nrows, int out_stride)
{
    constexpr int BR  = 16 * BLOCK / DOUT;  // rows per block
    constexpr int BRP = BR + 1;             // pad: LDS bank-conflict-free
    constexpr int KV  = DIN / 4;            // float4 chunks per input row
    constexpr int JT  = DOUT / 4;           // col groups

    __shared__ float xs[DIN * BRP];         // transposed x tile
    __shared__ float Ws[DIN * DOUT];

    const int tid  = threadIdx.x;
    const int row0 = blockIdx.x * BR;

    // stage W (contiguous float4 copy)
    for (int i = tid; i < DIN * DOUT / 4; i += BLOCK)
        ((float4*)Ws)[i] = ((const float4*)W)[i];

    // stage x transposed: xs[k*BRP + r] = x[row0+r][k]
    const int kv = tid % KV;
    for (int rr = tid / KV; rr < BR; rr += BLOCK / KV) {
        const int row = row0 + rr;
        float4 v = make_float4(0.f, 0.f, 0.f, 0.f);
        if (row < nrows)
            v = ((const float4*)x)[(long)row * KV + kv];
        xs[(kv * 4 + 0) * BRP + rr] = v.x;
        xs[(kv * 4 + 1) * BRP + rr] = v.y;
        xs[(kv * 4 + 2) * BRP + rr] = v.z;
        xs[(kv * 4 + 3) * BRP + rr] = v.w;
    }
    __syncthreads();

    const int jt = tid % JT;
    const int rt = tid / JT;

    float4 b4 = ((const float4*)bias)[jt];
    float acc[4][4];
    #pragma unroll
    for (int r = 0; r < 4; ++r) {
        acc[r][0] = b4.x; acc[r][1] = b4.y; acc[r][2] = b4.z; acc[r][3] = b4.w;
    }

    #pragma unroll 8
    for (int k = 0; k < DIN; ++k) {
        float4 w = ((const float4*)(Ws + k * DOUT))[jt];
        float xr[4];
        #pragma unroll
        for (int r = 0; r < 4; ++r) xr[r] = xs[k * BRP + rt * 4 + r];
        #pragma unroll
        for (int r = 0; r < 4; ++r) {
            acc[r][0] = fmaf(xr[r], w.x, acc[r][0]);
            acc[r][1] = fmaf(xr[r], w.y, acc[r][1]);
            acc[r][2] = fmaf(xr[r], w.z, acc[r][2]);
            acc[r][3] = fmaf(xr[r], w.w, acc[r][3]);
        }
    }

    #pragma unroll
    for (int r = 0; r < 4; ++r) {
        const int row = row0 + rt * 4 + r;
        if (row >= nrows) continue;
        float4 o = make_float4(acc[r][0], acc[r][1], acc[r][2], acc[r][3]);
        if (EDGEADD) {
            const int a = idxA[row];
            const int b = idxB[row];
            float4 ga = ((const float4*)(tabA + (long)a * DOUT))[jt];
            float4 gb = ((const float4*)(tabB + (long)b * DOUT))[jt];
            o.x += ga.x + gb.x; o.y += ga.y + gb.y;
            o.z += ga.z + gb.z; o.w += ga.w + gb.w;
        }
        if (RELU) {
            o.x = fmaxf(o.x, 0.f); o.y = fmaxf(o.y, 0.f);
            o.z = fmaxf(o.z, 0.f); o.w = fmaxf(o.w, 0.f);
        }
        *((float4*)(out + (long)row * out_stride) + jt) = o;
    }
}

// ---------------------------------------------------------------------------
extern "C" void kernel_launch(void* const* d_in, const int* in_sizes, int n_in,
                              void* d_out, int out_size, void* d_ws, size_t ws_size,
                              hipStream_t stream)
{
    const float* f_feat = (const float*)d_in[0];
    const float* b_feat = (const float*)d_in[1];
    const float* u_feat = (const float*)d_in[2];
    const float* v_feat = (const float*)d_in[3];
    const int* fw_src = (const int*)d_in[4];
    const int* fw_dst = (const int*)d_in[5];
    const int* bw_src = (const int*)d_in[6];
    const int* bw_dst = (const int*)d_in[7];
    const float* w_e  = (const float*)d_in[8];   const float* b_e  = (const float*)d_in[9];
    const float* w_u  = (const float*)d_in[10];  const float* b_u  = (const float*)d_in[11];
    const float* w_v  = (const float*)d_in[12];  const float* b_v  = (const float*)d_in[13];
    const float* w_au = (const float*)d_in[14];  const float* b_au = (const float*)d_in[15];
    const float* w_av = (const float*)d_in[16];  const float* b_av = (const float*)d_in[17];
    const float* w_Wu = (const float*)d_in[18];  const float* b_Wu = (const float*)d_in[19];
    const float* w_Wv = (const float*)d_in[20];  const float* b_Wv = (const float*)d_in[21];
    const float* w_Vu = (const float*)d_in[22];  const float* b_Vu = (const float*)d_in[23];
    const float* w_Vv = (const float*)d_in[24];  const float* b_Vv = (const float*)d_in[25];

    const int N = NNODES, E = NEDGES;

    // outputs: (hf, hb, hu, hv) concatenated flat
    float* out = (float*)d_out;
    float* hf = out;                       // [E,64]  (written LAST)
    float* hb = hf + (long)E * 64;         // [E,64]  (written LAST)
    float* hu = hb + (long)E * 64;         // [N,128]
    float* hv = hu + (long)N * 128;        // [N,128]

    // h_att_u / h_att_v staged in the hf region of d_out (2*N*128 = 5.12M
    // floats < E*64 = 12.8M). Consumed by the agg passes, then hf is
    // overwritten by the edge linears at the end.
    float* h_att_u = hf;                   // [N,128]
    float* h_att_v = h_att_u + (long)N * 128;

    // workspace layout:
    //   floats: 3*N*64 (he projections) + 2*N*128 (agg)           = 8.96M f
    //   ints:   2*(deg N + rowptr N+1 + cursor N) + 2*eidx E      = 0.52M i
    // total ~38 MB (previous 56.3 MB layout was accepted by harness)
    float* ws = (float*)d_ws;
    float* src_he_u = ws;                        // [N,64] (== dst_he_u)
    float* src_he_v = src_he_u + (long)N * 64;   // [N,64]
    float* dst_he_v = src_he_v + (long)N * 64;   // [N,64]
    float* agg_u    = dst_he_v + (long)N * 64;   // [N,128]
    float* agg_v    = agg_u    + (long)N * 128;  // [N,128]
    int*   ibase    = (int*)(agg_v + (long)N * 128);
    int* deg_b    = ibase;                 // [N]   zeroed (contiguous w/ deg_f)
    int* deg_f    = deg_b + N;             // [N]   zeroed
    int* rowptr_b = deg_f + N;             // [N+1]
    int* rowptr_f = rowptr_b + (N + 1);    // [N+1]
    int* cursor_b = rowptr_f + (N + 1);    // [N]
    int* cursor_f = cursor_b + N;          // [N]
    int* eidx_b   = cursor_f + N;          // [E]
    int* eidx_f   = eidx_b + E;            // [E]

    const size_t ws_need = (size_t)((long)8960000 + 520002 + 2) * sizeof(float);
    if (ws_size < ws_need) return;         // defensive: avoid OOB scribbling

    // zero deg_b/deg_f (2N ints = 40000 ints = 10000 float4, 16B-aligned)
    zero_kernel<<<dim3((2 * N / 4 + 255) / 256), dim3(256), 0, stream>>>(
        (float4*)deg_b, (long)2 * N / 4);

    const int gN64 = (N + 63) / 64;  // DOUT=64, BLOCK=256 -> BR=64
    const int gN32 = (N + 31) / 32;  // BR=32 variants
    const int gE64 = (E + 63) / 64;
    const int gE   = (E + 255) / 256;

    // --- CSR build (both directions) ---
    hist_kernel<<<dim3(gE), dim3(256), 0, stream>>>(bw_dst, deg_b, E);
    hist_kernel<<<dim3(gE), dim3(256), 0, stream>>>(fw_dst, deg_f, E);
    scan_kernel<<<dim3(1), dim3(1024), 0, stream>>>(deg_b, rowptr_b, cursor_b, N);
    scan_kernel<<<dim3(1), dim3(1024), 0, stream>>>(deg_f, rowptr_f, cursor_f, N);
    scatter_kernel<<<dim3(gE), dim3(256), 0, stream>>>(bw_dst, cursor_b, eidx_b, E);
    scatter_kernel<<<dim3(gE), dim3(256), 0, stream>>>(fw_dst, cursor_f, eidx_f, E);

    // --- node projections ---
    hipLaunchKernelGGL((linear_kernel<64,64,256,false,false>), dim3(gN64), dim3(256), 0, stream,
                       u_feat, w_u,  b_u,  nullptr, nullptr, nullptr, nullptr, src_he_u, N, 64);
    hipLaunchKernelGGL((linear_kernel<64,64,256,false,false>), dim3(gN64), dim3(256), 0, stream,
                       v_feat, w_v,  b_v,  nullptr, nullptr, nullptr, nullptr, src_he_v, N, 64);
    hipLaunchKernelGGL((linear_kernel<64,64,256,false,false>), dim3(gN64), dim3(256), 0, stream,
                       v_feat, w_u,  b_u,  nullptr, nullptr, nullptr, nullptr, dst_he_v, N, 64);
    hipLaunchKernelGGL((linear_kernel<64,128,256,false,false>), dim3(gN32), dim3(256), 0, stream,
                       u_feat, w_au, b_au, nullptr, nullptr, nullptr, nullptr, h_att_u, N, 128);
    hipLaunchKernelGGL((linear_kernel<64,128,256,false,false>), dim3(gN32), dim3(256), 0, stream,
                       v_feat, w_av, b_av, nullptr, nullptr, nullptr, nullptr, h_att_v, N, 128);

    // hu/hv left halves (direct to d_out, stride 128)
    hipLaunchKernelGGL((linear_kernel<64,64,256,false,false>), dim3(gN64), dim3(256), 0, stream,
                       u_feat, w_Vu, b_Vu, nullptr, nullptr, nullptr, nullptr, hu, N, 128);
    hipLaunchKernelGGL((linear_kernel<64,64,256,false,false>), dim3(gN64), dim3(256), 0, stream,
                       v_feat, w_Vv, b_Vv, nullptr, nullptr, nullptr, nullptr, hv, N, 128);

    // --- segmented attention aggregation (no atomics) ---
    agg_kernel<<<dim3(N), dim3(128), 0, stream>>>(
        v_feat, b_feat, h_att_u, bw_src, eidx_b, rowptr_b, agg_u);
    agg_kernel<<<dim3(N), dim3(128), 0, stream>>>(
        u_feat, f_feat, h_att_v, fw_src, eidx_f, rowptr_f, agg_v);

    // final: h_n = relu(agg @ w_W + b_W) -> right halves of hu/hv
    hipLaunchKernelGGL((linear_kernel<128,64,128,true,false>), dim3(gN32), dim3(128), 0, stream,
                       agg_u, w_Wu, b_Wu, nullptr, nullptr, nullptr, nullptr, hu + 64, N, 128);
    hipLaunchKernelGGL((linear_kernel<128,64,128,true,false>), dim3(gN32), dim3(128), 0, stream,
                       agg_v, w_Wv, b_Wv, nullptr, nullptr, nullptr, nullptr, hv + 64, N, 128);

    // edge outputs LAST (they overwrite the h_att scratch in hf):
    // hf = relu(b_feat@w_e + b_e + src_he_u[bw_src] + src_he_v[bw_dst])
    hipLaunchKernelGGL((linear_kernel<64,64,256,true,true>), dim3(gE64), dim3(256), 0, stream,
                       b_feat, w_e, b_e, src_he_u, src_he_v, bw_src, bw_dst, hf, E, 64);
    // hb = relu(f_feat@w_e + b_e + src_he_u[fw_src] + dst_he_v[fw_dst])
    hipLaunchKernelGGL((linear_kernel<64,64,256,true,true>), dim3(gE64), dim3(256), 0, stream,
                       f_feat, w_e, b_e, src_he_u, dst_he_v, fw_src, fw_dst, hb, E, 64);
}

// Round 5
// 525.420 us; speedup vs baseline: 1.3612x; 1.1806x over previous
//
#include <hip/hip_runtime.h>

#define NNODES 20000
#define NEDGES 200000

// ---------------------------------------------------------------------------
// Zero-fill (float4 granularity). n4 = number of float4 elements.
// ---------------------------------------------------------------------------
__global__ __launch_bounds__(256)
void zero_kernel(float4* __restrict__ p, long n4)
{
    long i = (long)blockIdx.x * 256 + threadIdx.x;
    if (i < n4) p[i] = make_float4(0.f, 0.f, 0.f, 0.f);
}

// ---------------------------------------------------------------------------
// CSR build, both directions batched via blockIdx.y / blockIdx.x(scan):
// histogram -> single-block-per-direction scan -> scatter
// ---------------------------------------------------------------------------
__global__ __launch_bounds__(256)
void hist2_kernel(const int* __restrict__ dst0, const int* __restrict__ dst1,
                  int* __restrict__ deg0, int* __restrict__ deg1, int n)
{
    const int e = blockIdx.x * 256 + threadIdx.x;
    if (e >= n) return;
    if (blockIdx.y == 0) atomicAdd(&deg0[dst0[e]], 1);
    else                 atomicAdd(&deg1[dst1[e]], 1);
}

// exclusive scan of deg -> rowptr[0..n], copy into cursor. One 1024-thread
// block per direction (gridDim.x == 2).
__global__ __launch_bounds__(1024)
void scan2_kernel(const int* __restrict__ deg0, const int* __restrict__ deg1,
                  int* __restrict__ rp0, int* __restrict__ rp1,
                  int* __restrict__ cur0, int* __restrict__ cur1, int n)
{
    const int* deg = blockIdx.x == 0 ? deg0 : deg1;
    int* rowptr    = blockIdx.x == 0 ? rp0  : rp1;
    int* cursor    = blockIdx.x == 0 ? cur0 : cur1;

    __shared__ int part[1024];
    const int t  = threadIdx.x;
    const int CH = (n + 1023) / 1024;
    const int base = t * CH;

    int s = 0;
    for (int i = 0; i < CH; ++i) {
        int idx = base + i;
        if (idx < n) s += deg[idx];
    }
    part[t] = s;
    __syncthreads();
    for (int off = 1; off < 1024; off <<= 1) {
        int v = 0;
        if (t >= off) v = part[t - off];
        __syncthreads();
        if (t >= off) part[t] += v;
        __syncthreads();
    }
    int run = (t == 0) ? 0 : part[t - 1];
    for (int i = 0; i < CH; ++i) {
        int idx = base + i;
        if (idx < n) {
            int dv = deg[idx];
            rowptr[idx] = run;
            cursor[idx] = run;
            run += dv;
        }
    }
    if (t == 1023) rowptr[n] = part[1023];
}

__global__ __launch_bounds__(256)
void scatter2_kernel(const int* __restrict__ dst0, const int* __restrict__ dst1,
                     int* __restrict__ cur0, int* __restrict__ cur1,
                     int* __restrict__ ei0, int* __restrict__ ei1, int n)
{
    const int e = blockIdx.x * 256 + threadIdx.x;
    if (e >= n) return;
    if (blockIdx.y == 0) { int p = atomicAdd(&cur0[dst0[e]], 1); ei0[p] = e; }
    else                 { int p = atomicAdd(&cur1[dst1[e]], 1); ei1[p] = e; }
}

// ---------------------------------------------------------------------------
// Segmented attention-aggregation, both directions batched (blockIdx.y).
// One 128-thread block per dst node; thread c owns channel c. Max-subtraction
// cancels algebraically; |x| small -> no fp32 overflow. Writes
// agg = (sum hve*p)/(sum p) once per node — no fp32 atomics.
// 2-deep (eidx, src) software prefetch hides the dependent-gather latency.
// ---------------------------------------------------------------------------
__global__ __launch_bounds__(128)
void agg2_kernel(const float* __restrict__ fn0, const float* __restrict__ fe0,
                 const float* __restrict__ ha0, const int* __restrict__ src0,
                 const int* __restrict__ ei0,  const int* __restrict__ rp0,
                 float* __restrict__ agg0,
                 const float* __restrict__ fn1, const float* __restrict__ fe1,
                 const float* __restrict__ ha1, const int* __restrict__ src1,
                 const int* __restrict__ ei1,  const int* __restrict__ rp1,
                 float* __restrict__ agg1)
{
    const int y = blockIdx.y;
    const float* feat_node = y == 0 ? fn0 : fn1;
    const float* feat_edge = y == 0 ? fe0 : fe1;
    const float* h_att     = y == 0 ? ha0 : ha1;
    const int*   src       = y == 0 ? src0 : src1;
    const int*   eidx      = y == 0 ? ei0 : ei1;
    const int*   rowptr    = y == 0 ? rp0 : rp1;
    float*       agg       = y == 0 ? agg0 : agg1;

    const int d = blockIdx.x;
    const int c = threadIdx.x;
    const int lo = rowptr[d], hi = rowptr[d + 1];
    const bool low = c < 64;
    float ssum = 0.f, anum = 0.f;

    int i = lo;
    if (i < hi) {
        int e = eidx[i];
        int s = src[e];
        for (;;) {
            const bool more = (i + 1 < hi);
            int e2 = 0, s2 = 0;
            if (more) { e2 = eidx[i + 1]; s2 = src[e2]; }
            const float hve = low ? feat_node[(long)s * 64 + c]
                                  : feat_edge[(long)e * 64 + (c - 64)];
            const float att = h_att[(long)s * 128 + c];
            const float p = __expf(hve * att);
            ssum += p;
            anum += hve * p;
            if (!more) break;
            e = e2; s = s2; ++i;
        }
    }
    agg[(long)d * 128 + c] = (hi > lo) ? anum / ssum : 0.f;
}

// ---------------------------------------------------------------------------
// Batched tiled linear: up to 5 independent (x, W, bias, out) problems of the
// same shape, selected by blockIdx.y. 4x4 per-thread micro-tile, x staged
// TRANSPOSED in LDS (stride BR+1, conflict-free), W staged in LDS.
// ---------------------------------------------------------------------------
struct LinArgs {
    const float* x[5];
    const float* W[5];
    const float* bias[5];
    float*       out[5];
    long         ostride[5];
};

template<int DIN, int DOUT, int BLOCK, bool RELU>
__global__ __launch_bounds__(BLOCK)
void lin_batch_kernel(LinArgs a, int nrows)
{
    constexpr int BR  = 16 * BLOCK / DOUT;
    constexpr int BRP = BR + 1;
    constexpr int KV  = DIN / 4;
    constexpr int JT  = DOUT / 4;

    const int y = blockIdx.y;
    const float* __restrict__ x    = a.x[y];
    const float* __restrict__ W    = a.W[y];
    const float* __restrict__ bias = a.bias[y];
    float* __restrict__ out        = a.out[y];
    const long ostride             = a.ostride[y];

    __shared__ float xs[DIN * BRP];
    __shared__ float Ws[DIN * DOUT];

    const int tid  = threadIdx.x;
    const int row0 = blockIdx.x * BR;

    for (int i = tid; i < DIN * DOUT / 4; i += BLOCK)
        ((float4*)Ws)[i] = ((const float4*)W)[i];

    const int kv = tid % KV;
    for (int rr = tid / KV; rr < BR; rr += BLOCK / KV) {
        const int row = row0 + rr;
        float4 v = make_float4(0.f, 0.f, 0.f, 0.f);
        if (row < nrows)
            v = ((const float4*)x)[(long)row * KV + kv];
        xs[(kv * 4 + 0) * BRP + rr] = v.x;
        xs[(kv * 4 + 1) * BRP + rr] = v.y;
        xs[(kv * 4 + 2) * BRP + rr] = v.z;
        xs[(kv * 4 + 3) * BRP + rr] = v.w;
    }
    __syncthreads();

    const int jt = tid % JT;
    const int rt = tid / JT;

    float4 b4 = ((const float4*)bias)[jt];
    float acc[4][4];
    #pragma unroll
    for (int r = 0; r < 4; ++r) {
        acc[r][0] = b4.x; acc[r][1] = b4.y; acc[r][2] = b4.z; acc[r][3] = b4.w;
    }

    #pragma unroll 8
    for (int k = 0; k < DIN; ++k) {
        float4 w = ((const float4*)(Ws + k * DOUT))[jt];
        float xr[4];
        #pragma unroll
        for (int r = 0; r < 4; ++r) xr[r] = xs[k * BRP + rt * 4 + r];
        #pragma unroll
        for (int r = 0; r < 4; ++r) {
            acc[r][0] = fmaf(xr[r], w.x, acc[r][0]);
            acc[r][1] = fmaf(xr[r], w.y, acc[r][1]);
            acc[r][2] = fmaf(xr[r], w.z, acc[r][2]);
            acc[r][3] = fmaf(xr[r], w.w, acc[r][3]);
        }
    }

    #pragma unroll
    for (int r = 0; r < 4; ++r) {
        const int row = row0 + rt * 4 + r;
        if (row >= nrows) continue;
        float4 o = make_float4(acc[r][0], acc[r][1], acc[r][2], acc[r][3]);
        if (RELU) {
            o.x = fmaxf(o.x, 0.f); o.y = fmaxf(o.y, 0.f);
            o.z = fmaxf(o.z, 0.f); o.w = fmaxf(o.w, 0.f);
        }
        *((float4*)(out + (long)row * ostride) + jt) = o;
    }
}

// ---------------------------------------------------------------------------
// Batched edge linear (both directions, blockIdx.y):
//   out = relu(x @ w_e + b_e + tabA[idxA[r]] + tabB[idxB[r]])
// ---------------------------------------------------------------------------
struct EdgeArgs {
    const float* x[2];
    const float* tabA[2];
    const float* tabB[2];
    const int*   idxA[2];
    const int*   idxB[2];
    float*       out[2];
};

__global__ __launch_bounds__(256)
void edge_batch_kernel(EdgeArgs a, const float* __restrict__ W,
                       const float* __restrict__ bias, int nrows)
{
    constexpr int DIN = 64, DOUT = 64, BLOCK = 256;
    constexpr int BR  = 16 * BLOCK / DOUT;   // 64
    constexpr int BRP = BR + 1;
    constexpr int KV  = DIN / 4;             // 16
    constexpr int JT  = DOUT / 4;            // 16

    const int y = blockIdx.y;
    const float* __restrict__ x    = a.x[y];
    const float* __restrict__ tabA = a.tabA[y];
    const float* __restrict__ tabB = a.tabB[y];
    const int* __restrict__ idxA   = a.idxA[y];
    const int* __restrict__ idxB   = a.idxB[y];
    float* __restrict__ out        = a.out[y];

    __shared__ float xs[DIN * BRP];
    __shared__ float Ws[DIN * DOUT];

    const int tid  = threadIdx.x;
    const int row0 = blockIdx.x * BR;

    for (int i = tid; i < DIN * DOUT / 4; i += BLOCK)
        ((float4*)Ws)[i] = ((const float4*)W)[i];

    const int kv = tid % KV;
    for (int rr = tid / KV; rr < BR; rr += BLOCK / KV) {
        const int row = row0 + rr;
        float4 v = make_float4(0.f, 0.f, 0.f, 0.f);
        if (row < nrows)
            v = ((const float4*)x)[(long)row * KV + kv];
        xs[(kv * 4 + 0) * BRP + rr] = v.x;
        xs[(kv * 4 + 1) * BRP + rr] = v.y;
        xs[(kv * 4 + 2) * BRP + rr] = v.z;
        xs[(kv * 4 + 3) * BRP + rr] = v.w;
    }
    __syncthreads();

    const int jt = tid % JT;
    const int rt = tid / JT;

    float4 b4 = ((const float4*)bias)[jt];
    float acc[4][4];
    #pragma unroll
    for (int r = 0; r < 4; ++r) {
        acc[r][0] = b4.x; acc[r][1] = b4.y; acc[r][2] = b4.z; acc[r][3] = b4.w;
    }

    #pragma unroll 8
    for (int k = 0; k < DIN; ++k) {
        float4 w = ((const float4*)(Ws + k * DOUT))[jt];
        float xr[4];
        #pragma unroll
        for (int r = 0; r < 4; ++r) xr[r] = xs[k * BRP + rt * 4 + r];
        #pragma unroll
        for (int r = 0; r < 4; ++r) {
            acc[r][0] = fmaf(xr[r], w.x, acc[r][0]);
            acc[r][1] = fmaf(xr[r], w.y, acc[r][1]);
            acc[r][2] = fmaf(xr[r], w.z, acc[r][2]);
            acc[r][3] = fmaf(xr[r], w.w, acc[r][3]);
        }
    }

    #pragma unroll
    for (int r = 0; r < 4; ++r) {
        const int row = row0 + rt * 4 + r;
        if (row >= nrows) continue;
        const int ia = idxA[row];
        const int ib = idxB[row];
        float4 ga = ((const float4*)(tabA + (long)ia * DOUT))[jt];
        float4 gb = ((const float4*)(tabB + (long)ib * DOUT))[jt];
        float4 o;
        o.x = fmaxf(acc[r][0] + ga.x + gb.x, 0.f);
        o.y = fmaxf(acc[r][1] + ga.y + gb.y, 0.f);
        o.z = fmaxf(acc[r][2] + ga.z + gb.z, 0.f);
        o.w = fmaxf(acc[r][3] + ga.w + gb.w, 0.f);
        *((float4*)(out + (long)row * DOUT) + jt) = o;
    }
}

// ---------------------------------------------------------------------------
extern "C" void kernel_launch(void* const* d_in, const int* in_sizes, int n_in,
                              void* d_out, int out_size, void* d_ws, size_t ws_size,
                              hipStream_t stream)
{
    const float* f_feat = (const float*)d_in[0];
    const float* b_feat = (const float*)d_in[1];
    const float* u_feat = (const float*)d_in[2];
    const float* v_feat = (const float*)d_in[3];
    const int* fw_src = (const int*)d_in[4];
    const int* fw_dst = (const int*)d_in[5];
    const int* bw_src = (const int*)d_in[6];
    const int* bw_dst = (const int*)d_in[7];
    const float* w_e  = (const float*)d_in[8];   const float* b_e  = (const float*)d_in[9];
    const float* w_u  = (const float*)d_in[10];  const float* b_u  = (const float*)d_in[11];
    const float* w_v  = (const float*)d_in[12];  const float* b_v  = (const float*)d_in[13];
    const float* w_au = (const float*)d_in[14];  const float* b_au = (const float*)d_in[15];
    const float* w_av = (const float*)d_in[16];  const float* b_av = (const float*)d_in[17];
    const float* w_Wu = (const float*)d_in[18];  const float* b_Wu = (const float*)d_in[19];
    const float* w_Wv = (const float*)d_in[20];  const float* b_Wv = (const float*)d_in[21];
    const float* w_Vu = (const float*)d_in[22];  const float* b_Vu = (const float*)d_in[23];
    const float* w_Vv = (const float*)d_in[24];  const float* b_Vv = (const float*)d_in[25];

    const int N = NNODES, E = NEDGES;

    // outputs: (hf, hb, hu, hv) concatenated flat
    float* out = (float*)d_out;
    float* hf = out;                       // [E,64]  (written LAST)
    float* hb = hf + (long)E * 64;         // [E,64]  (written LAST)
    float* hu = hb + (long)E * 64;         // [N,128]
    float* hv = hu + (long)N * 128;        // [N,128]

    // h_att_u / h_att_v staged in the hf region of d_out (2*N*128 floats
    // < E*64). Consumed by agg, then hf overwritten by the edge batch LAST.
    float* h_att_u = hf;                   // [N,128]
    float* h_att_v = h_att_u + (long)N * 128;

    // workspace: floats 3*N*64 + 2*N*128 = 8.96M; ints 6N+2+2E = 0.52M
    float* ws = (float*)d_ws;
    float* src_he_u = ws;                        // [N,64] (== dst_he_u)
    float* src_he_v = src_he_u + (long)N * 64;   // [N,64]
    float* dst_he_v = src_he_v + (long)N * 64;   // [N,64]
    float* agg_u    = dst_he_v + (long)N * 64;   // [N,128]
    float* agg_v    = agg_u    + (long)N * 128;  // [N,128]
    int*   ibase    = (int*)(agg_v + (long)N * 128);
    int* deg_b    = ibase;                 // [N] zeroed
    int* deg_f    = deg_b + N;             // [N] zeroed
    int* rowptr_b = deg_f + N;             // [N+1]
    int* rowptr_f = rowptr_b + (N + 1);    // [N+1]
    int* cursor_b = rowptr_f + (N + 1);    // [N]
    int* cursor_f = cursor_b + N;          // [N]
    int* eidx_b   = cursor_f + N;          // [E]
    int* eidx_f   = eidx_b + E;            // [E]

    const size_t ws_need = (size_t)((long)8960000 + 520002 + 2) * sizeof(float);
    if (ws_size < ws_need) return;

    // 1) zero deg_b/deg_f (2N ints = 10000 float4)
    zero_kernel<<<dim3((2 * N / 4 + 255) / 256), dim3(256), 0, stream>>>(
        (float4*)deg_b, (long)2 * N / 4);

    const int gN64 = (N + 63) / 64;
    const int gN32 = (N + 31) / 32;
    const int gE64 = (E + 63) / 64;
    const int gE   = (E + 255) / 256;

    // 2-4) CSR build, both directions per dispatch
    hist2_kernel<<<dim3(gE, 2), dim3(256), 0, stream>>>(
        bw_dst, fw_dst, deg_b, deg_f, E);
    scan2_kernel<<<dim3(2), dim3(1024), 0, stream>>>(
        deg_b, deg_f, rowptr_b, rowptr_f, cursor_b, cursor_f, N);
    scatter2_kernel<<<dim3(gE, 2), dim3(256), 0, stream>>>(
        bw_dst, fw_dst, cursor_b, cursor_f, eidx_b, eidx_f, E);

    // 5) five 64->64 node linears in one dispatch
    {
        LinArgs a;
        a.x[0]=u_feat; a.W[0]=w_u;  a.bias[0]=b_u;  a.out[0]=src_he_u; a.ostride[0]=64;
        a.x[1]=v_feat; a.W[1]=w_v;  a.bias[1]=b_v;  a.out[1]=src_he_v; a.ostride[1]=64;
        a.x[2]=v_feat; a.W[2]=w_u;  a.bias[2]=b_u;  a.out[2]=dst_he_v; a.ostride[2]=64;
        a.x[3]=u_feat; a.W[3]=w_Vu; a.bias[3]=b_Vu; a.out[3]=hu;       a.ostride[3]=128;
        a.x[4]=v_feat; a.W[4]=w_Vv; a.bias[4]=b_Vv; a.out[4]=hv;       a.ostride[4]=128;
        lin_batch_kernel<64,64,256,false><<<dim3(gN64, 5), dim3(256), 0, stream>>>(a, N);
    }

    // 6) two 64->128 attention projections in one dispatch
    {
        LinArgs a = {};
        a.x[0]=u_feat; a.W[0]=w_au; a.bias[0]=b_au; a.out[0]=h_att_u; a.ostride[0]=128;
        a.x[1]=v_feat; a.W[1]=w_av; a.bias[1]=b_av; a.out[1]=h_att_v; a.ostride[1]=128;
        lin_batch_kernel<64,128,256,false><<<dim3(gN32, 2), dim3(256), 0, stream>>>(a, N);
    }

    // 7) segmented attention aggregation, both directions, no atomics
    agg2_kernel<<<dim3(N, 2), dim3(128), 0, stream>>>(
        v_feat, b_feat, h_att_u, bw_src, eidx_b, rowptr_b, agg_u,
        u_feat, f_feat, h_att_v, fw_src, eidx_f, rowptr_f, agg_v);

    // 8) two 128->64 final linears in one dispatch (right halves of hu/hv)
    {
        LinArgs a = {};
        a.x[0]=agg_u; a.W[0]=w_Wu; a.bias[0]=b_Wu; a.out[0]=hu + 64; a.ostride[0]=128;
        a.x[1]=agg_v; a.W[1]=w_Wv; a.bias[1]=b_Wv; a.out[1]=hv + 64; a.ostride[1]=128;
        lin_batch_kernel<128,64,128,true><<<dim3(gN32, 2), dim3(128), 0, stream>>>(a, N);
    }

    // 9) edge outputs LAST (overwrite h_att scratch in hf):
    //    hf = relu(b_feat@w_e + b_e + src_he_u[bw_src] + src_he_v[bw_dst])
    //    hb = relu(f_feat@w_e + b_e + src_he_u[fw_src] + dst_he_v[fw_dst])
    {
        EdgeArgs a;
        a.x[0]=b_feat; a.tabA[0]=src_he_u; a.tabB[0]=src_he_v;
        a.idxA[0]=bw_src; a.idxB[0]=bw_dst; a.out[0]=hf;
        a.x[1]=f_feat; a.tabA[1]=src_he_u; a.tabB[1]=dst_he_v;
        a.idxA[1]=fw_src; a.idxB[1]=fw_dst; a.out[1]=hb;
        edge_batch_kernel<<<dim3(gE64, 2), dim3(256), 0, stream>>>(a, w_e, b_e, E);
    }
}

// Round 6
// 479.708 us; speedup vs baseline: 1.4909x; 1.0953x over previous
//
#include <hip/hip_runtime.h>

#define NNODES 20000
#define NEDGES 200000

// ---------------------------------------------------------------------------
// Zero-fill (float4 granularity). n4 = number of float4 elements.
// ---------------------------------------------------------------------------
__global__ __launch_bounds__(256)
void zero_kernel(float4* __restrict__ p, long n4)
{
    long i = (long)blockIdx.x * 256 + threadIdx.x;
    if (i < n4) p[i] = make_float4(0.f, 0.f, 0.f, 0.f);
}

// ---------------------------------------------------------------------------
// CSR build, both directions batched via blockIdx.y / blockIdx.x(scan):
// histogram -> single-block-per-direction scan -> scatter
// ---------------------------------------------------------------------------
__global__ __launch_bounds__(256)
void hist2_kernel(const int* __restrict__ dst0, const int* __restrict__ dst1,
                  int* __restrict__ deg0, int* __restrict__ deg1, int n)
{
    const int e = blockIdx.x * 256 + threadIdx.x;
    if (e >= n) return;
    if (blockIdx.y == 0) atomicAdd(&deg0[dst0[e]], 1);
    else                 atomicAdd(&deg1[dst1[e]], 1);
}

// exclusive scan of deg -> rowptr[0..n], copy into cursor. One 1024-thread
// block per direction (gridDim.x == 2).
__global__ __launch_bounds__(1024)
void scan2_kernel(const int* __restrict__ deg0, const int* __restrict__ deg1,
                  int* __restrict__ rp0, int* __restrict__ rp1,
                  int* __restrict__ cur0, int* __restrict__ cur1, int n)
{
    const int* deg = blockIdx.x == 0 ? deg0 : deg1;
    int* rowptr    = blockIdx.x == 0 ? rp0  : rp1;
    int* cursor    = blockIdx.x == 0 ? cur0 : cur1;

    __shared__ int part[1024];
    const int t  = threadIdx.x;
    const int CH = (n + 1023) / 1024;
    const int base = t * CH;

    int s = 0;
    for (int i = 0; i < CH; ++i) {
        int idx = base + i;
        if (idx < n) s += deg[idx];
    }
    part[t] = s;
    __syncthreads();
    for (int off = 1; off < 1024; off <<= 1) {
        int v = 0;
        if (t >= off) v = part[t - off];
        __syncthreads();
        if (t >= off) part[t] += v;
        __syncthreads();
    }
    int run = (t == 0) ? 0 : part[t - 1];
    for (int i = 0; i < CH; ++i) {
        int idx = base + i;
        if (idx < n) {
            int dv = deg[idx];
            rowptr[idx] = run;
            cursor[idx] = run;
            run += dv;
        }
    }
    if (t == 1023) rowptr[n] = part[1023];
}

__global__ __launch_bounds__(256)
void scatter2_kernel(const int* __restrict__ dst0, const int* __restrict__ dst1,
                     int* __restrict__ cur0, int* __restrict__ cur1,
                     int* __restrict__ ei0, int* __restrict__ ei1, int n)
{
    const int e = blockIdx.x * 256 + threadIdx.x;
    if (e >= n) return;
    if (blockIdx.y == 0) { int p = atomicAdd(&cur0[dst0[e]], 1); ei0[p] = e; }
    else                 { int p = atomicAdd(&cur1[dst1[e]], 1); ei1[p] = e; }
}

// ---------------------------------------------------------------------------
// Segmented attention-aggregation v3, both directions batched (blockIdx.y).
// One 128-thread block per dst node; thread c owns channel c.
// Round-5 rocprof: v2 was MLP/latency-bound (122 us, 1.85 TB/s, VALU 13%).
// Fix: (1) eidx[lo..hi) is CONTIGUOUS (CSR) -> lane-parallel coalesced load
// of the whole segment's indices + lane-parallel src gather into LDS, killing
// the serial eidx->src chain; (2) 4-way unrolled row gathers: 8 independent
// row loads in flight per wave before the exp/fma block.
// Max-subtraction cancels algebraically; |x| small -> no fp32 overflow.
// Writes agg = (sum hve*p)/(sum p) once per node — no fp32 atomics.
// ---------------------------------------------------------------------------
__global__ __launch_bounds__(128)
void agg3_kernel(const float* __restrict__ fn0, const float* __restrict__ fe0,
                 const float* __restrict__ ha0, const int* __restrict__ src0,
                 const int* __restrict__ ei0,  const int* __restrict__ rp0,
                 float* __restrict__ agg0,
                 const float* __restrict__ fn1, const float* __restrict__ fe1,
                 const float* __restrict__ ha1, const int* __restrict__ src1,
                 const int* __restrict__ ei1,  const int* __restrict__ rp1,
                 float* __restrict__ agg1)
{
    const int y = blockIdx.y;
    const float* __restrict__ feat_node = y == 0 ? fn0 : fn1;
    const float* __restrict__ feat_edge = y == 0 ? fe0 : fe1;
    const float* __restrict__ h_att     = y == 0 ? ha0 : ha1;
    const int*   __restrict__ src       = y == 0 ? src0 : src1;
    const int*   __restrict__ eidx      = y == 0 ? ei0 : ei1;
    const int*   __restrict__ rowptr    = y == 0 ? rp0 : rp1;
    float*       __restrict__ agg       = y == 0 ? agg0 : agg1;

    const int d = blockIdx.x;
    const int c = threadIdx.x;
    const int lo = rowptr[d], hi = rowptr[d + 1];
    const bool low = c < 64;

    __shared__ int se[64];
    __shared__ int ss[64];

    float ssum = 0.f, anum = 0.f;

    for (int base = lo; base < hi; base += 64) {
        const int cnt = min(64, hi - base);
        if (c < cnt) {
            const int e = eidx[base + c];   // coalesced: contiguous in CSR
            se[c] = e;
            ss[c] = src[e];                 // lane-parallel gather
        }
        __syncthreads();

        int i = 0;
        for (; i + 4 <= cnt; i += 4) {
            float hv[4], at[4];
            #pragma unroll
            for (int j = 0; j < 4; ++j) {
                const int e = se[i + j];    // LDS broadcast (same addr)
                const int s = ss[i + j];
                hv[j] = low ? feat_node[(long)s * 64 + c]
                            : feat_edge[(long)e * 64 + (c - 64)];
                at[j] = h_att[(long)s * 128 + c];
            }
            #pragma unroll
            for (int j = 0; j < 4; ++j) {
                const float p = __expf(hv[j] * at[j]);
                ssum += p;
                anum += hv[j] * p;
            }
        }
        for (; i < cnt; ++i) {
            const int e = se[i];
            const int s = ss[i];
            const float hvv = low ? feat_node[(long)s * 64 + c]
                                  : feat_edge[(long)e * 64 + (c - 64)];
            const float att = h_att[(long)s * 128 + c];
            const float p = __expf(hvv * att);
            ssum += p;
            anum += hvv * p;
        }
        __syncthreads();
    }
    agg[(long)d * 128 + c] = (hi > lo) ? anum / ssum : 0.f;
}

// ---------------------------------------------------------------------------
// Batched tiled linear: up to 5 independent (x, W, bias, out) problems of the
// same shape, selected by blockIdx.y. 4x4 per-thread micro-tile, x staged
// TRANSPOSED in LDS (stride BR+1, conflict-free), W staged in LDS.
// ---------------------------------------------------------------------------
struct LinArgs {
    const float* x[5];
    const float* W[5];
    const float* bias[5];
    float*       out[5];
    long         ostride[5];
};

template<int DIN, int DOUT, int BLOCK, bool RELU>
__global__ __launch_bounds__(BLOCK)
void lin_batch_kernel(LinArgs a, int nrows)
{
    constexpr int BR  = 16 * BLOCK / DOUT;
    constexpr int BRP = BR + 1;
    constexpr int KV  = DIN / 4;
    constexpr int JT  = DOUT / 4;

    const int y = blockIdx.y;
    const float* __restrict__ x    = a.x[y];
    const float* __restrict__ W    = a.W[y];
    const float* __restrict__ bias = a.bias[y];
    float* __restrict__ out        = a.out[y];
    const long ostride             = a.ostride[y];

    __shared__ float xs[DIN * BRP];
    __shared__ float Ws[DIN * DOUT];

    const int tid  = threadIdx.x;
    const int row0 = blockIdx.x * BR;

    for (int i = tid; i < DIN * DOUT / 4; i += BLOCK)
        ((float4*)Ws)[i] = ((const float4*)W)[i];

    const int kv = tid % KV;
    for (int rr = tid / KV; rr < BR; rr += BLOCK / KV) {
        const int row = row0 + rr;
        float4 v = make_float4(0.f, 0.f, 0.f, 0.f);
        if (row < nrows)
            v = ((const float4*)x)[(long)row * KV + kv];
        xs[(kv * 4 + 0) * BRP + rr] = v.x;
        xs[(kv * 4 + 1) * BRP + rr] = v.y;
        xs[(kv * 4 + 2) * BRP + rr] = v.z;
        xs[(kv * 4 + 3) * BRP + rr] = v.w;
    }
    __syncthreads();

    const int jt = tid % JT;
    const int rt = tid / JT;

    float4 b4 = ((const float4*)bias)[jt];
    float acc[4][4];
    #pragma unroll
    for (int r = 0; r < 4; ++r) {
        acc[r][0] = b4.x; acc[r][1] = b4.y; acc[r][2] = b4.z; acc[r][3] = b4.w;
    }

    #pragma unroll 8
    for (int k = 0; k < DIN; ++k) {
        float4 w = ((const float4*)(Ws + k * DOUT))[jt];
        float xr[4];
        #pragma unroll
        for (int r = 0; r < 4; ++r) xr[r] = xs[k * BRP + rt * 4 + r];
        #pragma unroll
        for (int r = 0; r < 4; ++r) {
            acc[r][0] = fmaf(xr[r], w.x, acc[r][0]);
            acc[r][1] = fmaf(xr[r], w.y, acc[r][1]);
            acc[r][2] = fmaf(xr[r], w.z, acc[r][2]);
            acc[r][3] = fmaf(xr[r], w.w, acc[r][3]);
        }
    }

    #pragma unroll
    for (int r = 0; r < 4; ++r) {
        const int row = row0 + rt * 4 + r;
        if (row >= nrows) continue;
        float4 o = make_float4(acc[r][0], acc[r][1], acc[r][2], acc[r][3]);
        if (RELU) {
            o.x = fmaxf(o.x, 0.f); o.y = fmaxf(o.y, 0.f);
            o.z = fmaxf(o.z, 0.f); o.w = fmaxf(o.w, 0.f);
        }
        *((float4*)(out + (long)row * ostride) + jt) = o;
    }
}

// ---------------------------------------------------------------------------
// Batched edge linear (both directions, blockIdx.y):
//   out = relu(x @ w_e + b_e + tabA[idxA[r]] + tabB[idxB[r]])
// ---------------------------------------------------------------------------
struct EdgeArgs {
    const float* x[2];
    const float* tabA[2];
    const float* tabB[2];
    const int*   idxA[2];
    const int*   idxB[2];
    float*       out[2];
};

__global__ __launch_bounds__(256)
void edge_batch_kernel(EdgeArgs a, const float* __restrict__ W,
                       const float* __restrict__ bias, int nrows)
{
    constexpr int DIN = 64, DOUT = 64, BLOCK = 256;
    constexpr int BR  = 16 * BLOCK / DOUT;   // 64
    constexpr int BRP = BR + 1;
    constexpr int KV  = DIN / 4;             // 16
    constexpr int JT  = DOUT / 4;            // 16

    const int y = blockIdx.y;
    const float* __restrict__ x    = a.x[y];
    const float* __restrict__ tabA = a.tabA[y];
    const float* __restrict__ tabB = a.tabB[y];
    const int* __restrict__ idxA   = a.idxA[y];
    const int* __restrict__ idxB   = a.idxB[y];
    float* __restrict__ out        = a.out[y];

    __shared__ float xs[DIN * BRP];
    __shared__ float Ws[DIN * DOUT];

    const int tid  = threadIdx.x;
    const int row0 = blockIdx.x * BR;

    for (int i = tid; i < DIN * DOUT / 4; i += BLOCK)
        ((float4*)Ws)[i] = ((const float4*)W)[i];

    const int kv = tid % KV;
    for (int rr = tid / KV; rr < BR; rr += BLOCK / KV) {
        const int row = row0 + rr;
        float4 v = make_float4(0.f, 0.f, 0.f, 0.f);
        if (row < nrows)
            v = ((const float4*)x)[(long)row * KV + kv];
        xs[(kv * 4 + 0) * BRP + rr] = v.x;
        xs[(kv * 4 + 1) * BRP + rr] = v.y;
        xs[(kv * 4 + 2) * BRP + rr] = v.z;
        xs[(kv * 4 + 3) * BRP + rr] = v.w;
    }
    __syncthreads();

    const int jt = tid % JT;
    const int rt = tid / JT;

    float4 b4 = ((const float4*)bias)[jt];
    float acc[4][4];
    #pragma unroll
    for (int r = 0; r < 4; ++r) {
        acc[r][0] = b4.x; acc[r][1] = b4.y; acc[r][2] = b4.z; acc[r][3] = b4.w;
    }

    #pragma unroll 8
    for (int k = 0; k < DIN; ++k) {
        float4 w = ((const float4*)(Ws + k * DOUT))[jt];
        float xr[4];
        #pragma unroll
        for (int r = 0; r < 4; ++r) xr[r] = xs[k * BRP + rt * 4 + r];
        #pragma unroll
        for (int r = 0; r < 4; ++r) {
            acc[r][0] = fmaf(xr[r], w.x, acc[r][0]);
            acc[r][1] = fmaf(xr[r], w.y, acc[r][1]);
            acc[r][2] = fmaf(xr[r], w.z, acc[r][2]);
            acc[r][3] = fmaf(xr[r], w.w, acc[r][3]);
        }
    }

    #pragma unroll
    for (int r = 0; r < 4; ++r) {
        const int row = row0 + rt * 4 + r;
        if (row >= nrows) continue;
        const int ia = idxA[row];
        const int ib = idxB[row];
        float4 ga = ((const float4*)(tabA + (long)ia * DOUT))[jt];
        float4 gb = ((const float4*)(tabB + (long)ib * DOUT))[jt];
        float4 o;
        o.x = fmaxf(acc[r][0] + ga.x + gb.x, 0.f);
        o.y = fmaxf(acc[r][1] + ga.y + gb.y, 0.f);
        o.z = fmaxf(acc[r][2] + ga.z + gb.z, 0.f);
        o.w = fmaxf(acc[r][3] + ga.w + gb.w, 0.f);
        *((float4*)(out + (long)row * DOUT) + jt) = o;
    }
}

// ---------------------------------------------------------------------------
extern "C" void kernel_launch(void* const* d_in, const int* in_sizes, int n_in,
                              void* d_out, int out_size, void* d_ws, size_t ws_size,
                              hipStream_t stream)
{
    const float* f_feat = (const float*)d_in[0];
    const float* b_feat = (const float*)d_in[1];
    const float* u_feat = (const float*)d_in[2];
    const float* v_feat = (const float*)d_in[3];
    const int* fw_src = (const int*)d_in[4];
    const int* fw_dst = (const int*)d_in[5];
    const int* bw_src = (const int*)d_in[6];
    const int* bw_dst = (const int*)d_in[7];
    const float* w_e  = (const float*)d_in[8];   const float* b_e  = (const float*)d_in[9];
    const float* w_u  = (const float*)d_in[10];  const float* b_u  = (const float*)d_in[11];
    const float* w_v  = (const float*)d_in[12];  const float* b_v  = (const float*)d_in[13];
    const float* w_au = (const float*)d_in[14];  const float* b_au = (const float*)d_in[15];
    const float* w_av = (const float*)d_in[16];  const float* b_av = (const float*)d_in[17];
    const float* w_Wu = (const float*)d_in[18];  const float* b_Wu = (const float*)d_in[19];
    const float* w_Wv = (const float*)d_in[20];  const float* b_Wv = (const float*)d_in[21];
    const float* w_Vu = (const float*)d_in[22];  const float* b_Vu = (const float*)d_in[23];
    const float* w_Vv = (const float*)d_in[24];  const float* b_Vv = (const float*)d_in[25];

    const int N = NNODES, E = NEDGES;

    // outputs: (hf, hb, hu, hv) concatenated flat
    float* out = (float*)d_out;
    float* hf = out;                       // [E,64]  (written LAST)
    float* hb = hf + (long)E * 64;         // [E,64]  (written LAST)
    float* hu = hb + (long)E * 64;         // [N,128]
    float* hv = hu + (long)N * 128;        // [N,128]

    // h_att_u / h_att_v staged in the hf region of d_out (2*N*128 floats
    // < E*64). Consumed by agg, then hf overwritten by the edge batch LAST.
    float* h_att_u = hf;                   // [N,128]
    float* h_att_v = h_att_u + (long)N * 128;

    // workspace: floats 3*N*64 + 2*N*128 = 8.96M; ints 6N+2+2E = 0.52M
    float* ws = (float*)d_ws;
    float* src_he_u = ws;                        // [N,64] (== dst_he_u)
    float* src_he_v = src_he_u + (long)N * 64;   // [N,64]
    float* dst_he_v = src_he_v + (long)N * 64;   // [N,64]
    float* agg_u    = dst_he_v + (long)N * 64;   // [N,128]
    float* agg_v    = agg_u    + (long)N * 128;  // [N,128]
    int*   ibase    = (int*)(agg_v + (long)N * 128);
    int* deg_b    = ibase;                 // [N] zeroed
    int* deg_f    = deg_b + N;             // [N] zeroed
    int* rowptr_b = deg_f + N;             // [N+1]
    int* rowptr_f = rowptr_b + (N + 1);    // [N+1]
    int* cursor_b = rowptr_f + (N + 1);    // [N]
    int* cursor_f = cursor_b + N;          // [N]
    int* eidx_b   = cursor_f + N;          // [E]
    int* eidx_f   = eidx_b + E;            // [E]

    const size_t ws_need = (size_t)((long)8960000 + 520002 + 2) * sizeof(float);
    if (ws_size < ws_need) return;

    // 1) zero deg_b/deg_f (2N ints = 10000 float4)
    zero_kernel<<<dim3((2 * N / 4 + 255) / 256), dim3(256), 0, stream>>>(
        (float4*)deg_b, (long)2 * N / 4);

    const int gN64 = (N + 63) / 64;
    const int gN32 = (N + 31) / 32;
    const int gE64 = (E + 63) / 64;
    const int gE   = (E + 255) / 256;

    // 2-4) CSR build, both directions per dispatch
    hist2_kernel<<<dim3(gE, 2), dim3(256), 0, stream>>>(
        bw_dst, fw_dst, deg_b, deg_f, E);
    scan2_kernel<<<dim3(2), dim3(1024), 0, stream>>>(
        deg_b, deg_f, rowptr_b, rowptr_f, cursor_b, cursor_f, N);
    scatter2_kernel<<<dim3(gE, 2), dim3(256), 0, stream>>>(
        bw_dst, fw_dst, cursor_b, cursor_f, eidx_b, eidx_f, E);

    // 5) five 64->64 node linears in one dispatch
    {
        LinArgs a;
        a.x[0]=u_feat; a.W[0]=w_u;  a.bias[0]=b_u;  a.out[0]=src_he_u; a.ostride[0]=64;
        a.x[1]=v_feat; a.W[1]=w_v;  a.bias[1]=b_v;  a.out[1]=src_he_v; a.ostride[1]=64;
        a.x[2]=v_feat; a.W[2]=w_u;  a.bias[2]=b_u;  a.out[2]=dst_he_v; a.ostride[2]=64;
        a.x[3]=u_feat; a.W[3]=w_Vu; a.bias[3]=b_Vu; a.out[3]=hu;       a.ostride[3]=128;
        a.x[4]=v_feat; a.W[4]=w_Vv; a.bias[4]=b_Vv; a.out[4]=hv;       a.ostride[4]=128;
        lin_batch_kernel<64,64,256,false><<<dim3(gN64, 5), dim3(256), 0, stream>>>(a, N);
    }

    // 6) two 64->128 attention projections in one dispatch
    {
        LinArgs a = {};
        a.x[0]=u_feat; a.W[0]=w_au; a.bias[0]=b_au; a.out[0]=h_att_u; a.ostride[0]=128;
        a.x[1]=v_feat; a.W[1]=w_av; a.bias[1]=b_av; a.out[1]=h_att_v; a.ostride[1]=128;
        lin_batch_kernel<64,128,256,false><<<dim3(gN32, 2), dim3(256), 0, stream>>>(a, N);
    }

    // 7) segmented attention aggregation v3, both directions, no atomics
    agg3_kernel<<<dim3(N, 2), dim3(128), 0, stream>>>(
        v_feat, b_feat, h_att_u, bw_src, eidx_b, rowptr_b, agg_u,
        u_feat, f_feat, h_att_v, fw_src, eidx_f, rowptr_f, agg_v);

    // 8) two 128->64 final linears in one dispatch (right halves of hu/hv)
    {
        LinArgs a = {};
        a.x[0]=agg_u; a.W[0]=w_Wu; a.bias[0]=b_Wu; a.out[0]=hu + 64; a.ostride[0]=128;
        a.x[1]=agg_v; a.W[1]=w_Wv; a.bias[1]=b_Wv; a.out[1]=hv + 64; a.ostride[1]=128;
        lin_batch_kernel<128,64,128,true><<<dim3(gN32, 2), dim3(128), 0, stream>>>(a, N);
    }

    // 9) edge outputs LAST (overwrite h_att scratch in hf):
    //    hf = relu(b_feat@w_e + b_e + src_he_u[bw_src] + src_he_v[bw_dst])
    //    hb = relu(f_feat@w_e + b_e + src_he_u[fw_src] + dst_he_v[fw_dst])
    {
        EdgeArgs a;
        a.x[0]=b_feat; a.tabA[0]=src_he_u; a.tabB[0]=src_he_v;
        a.idxA[0]=bw_src; a.idxB[0]=bw_dst; a.out[0]=hf;
        a.x[1]=f_feat; a.tabA[1]=src_he_u; a.tabB[1]=dst_he_v;
        a.idxA[1]=fw_src; a.idxB[1]=fw_dst; a.out[1]=hb;
        edge_batch_kernel<<<dim3(gE64, 2), dim3(256), 0, stream>>>(a, w_e, b_e, E);
    }
}